// Round 13
// baseline (79.347 us; speedup 1.0000x reference)
//
#include <hip/hip_runtime.h>
#include <math.h>

namespace {
constexpr int COARSE = 32;
constexpr int NPT    = 767;   // N_INT - 1
constexpr int NRAYS  = 256;
constexpr int JMAX   = 224;                    // j < 221.7 provable in-cube bound
constexpr int SEGS   = JMAX / 4;               // 56 (4 waves/block, 1 pt/wave)
constexpr int GATHER_BLOCKS = NRAYS * SEGS;    // 14336 (% 8 == 0)
constexpr int WS_RAY_STRIDE = 256;
constexpr int WS_PLANE = NRAYS * WS_RAY_STRIDE;            // 65536 floats/plane
constexpr int WS_TAB_OFF_F4 = (3 * WS_PLANE) / 4;          // 49152 (float4 idx)
constexpr int WS_RAYDAT_OFF_F = 3 * WS_PLANE + NRAYS*512*4; // 720896 (float idx)
constexpr double VOXEL_D = 1.3 * 2.0 / 32.0 / 4.0;
constexpr float  VOXEL_F  = (float)VOXEL_D;
constexpr float  INV_VOXEL = (float)(1.0 / VOXEL_D);
constexpr float  STEP_F   = (float)(VOXEL_D / 2.0);
constexpr float  RAD      = 1.3f;
}

// ---------------------------------------------------------------------------
// Init: one block per ray. {start, jexit, dist} + per-ray 512-float4 fold
// table into ws.
// ---------------------------------------------------------------------------
__global__ __launch_bounds__(256)
void shdict_init(const float* __restrict__ rays_o,
                 const float* __restrict__ rays_d,
                 float* __restrict__ ws)
{
  const int ray = blockIdx.x;
  const float ox = rays_o[ray*3+0], oy = rays_o[ray*3+1], oz = rays_o[ray*3+2];
  const float dx = rays_d[ray*3+0], dy = rays_d[ray*3+1], dz = rays_d[ray*3+2];

  const float ax0 = (RAD - ox)/dx, ax1 = (-RAD - ox)/dx;
  const float ay0 = (RAD - oy)/dy, ay1 = (-RAD - oy)/dy;
  const float az0 = (RAD - oz)/dz, az1 = (-RAD - oz)/dz;
  const float start = fmaxf(fmaxf(fminf(ax0,ax1), fminf(ay0,ay1)), fminf(az0,az1));
  const float texit = fminf(fminf(fmaxf(ax0,ax1), fmaxf(ay0,ay1)), fmaxf(az0,az1));
  const float dnorm = sqrtf(dx*dx + dy*dy + dz*dz);
  const float inx = dx/dnorm, iny = dy/dnorm, inz = dz/dnorm;

  if (threadIdx.x == 0) {
    float* rs = ws + WS_RAYDAT_OFF_F + ray*4;
    rs[0] = start;
    rs[1] = (texit - start) / STEP_F;   // jexit
    rs[2] = STEP_F * dnorm;             // dist
    rs[3] = 0.f;
  }

  float4* tab = (float4*)ws + WS_TAB_OFF_F4 + (size_t)ray * 512;
  for (int tix = threadIdx.x; tix < 512; tix += 256) {
    const int ch = tix >> 7;
    const int fi = tix & 127;
    float vv[4];
    #pragma unroll
    for (int comp = 0; comp < 4; ++comp) {
      float val = 0.f;
      if (fi < 112) {
        const int e = 4*fi + comp;
        const int d = e % 28;
        const int dm = d % 9;
        const float shv =
          dm==0 ?  0.28209479177387814f :
          dm==1 ? -0.4886025119029199f*iny :
          dm==2 ?  0.4886025119029199f*inz :
          dm==3 ? -0.4886025119029199f*inx :
          dm==4 ?  1.0925484305920792f*inx*iny :
          dm==5 ? -1.0925484305920792f*iny*inz :
          dm==6 ?  0.31539156525252005f*(2.0f*inz*inz - inx*inx - iny*iny) :
          dm==7 ? -1.0925484305920792f*inx*inz :
                   0.5462742152960396f*(inx*inx - iny*iny);
        if (d == 27) { if (ch == 3) val = 1.0f; }
        else if (d/9 == ch) val = shv;
      }
      vv[comp] = val;
    }
    float4 v; v.x = vv[0]; v.y = vv[1]; v.z = vv[2]; v.w = vv[3];
    tab[tix] = v;
  }
}

// ---------------------------------------------------------------------------
// Gather: R11 structure (champion, 74us) + ONE change: the 8 epilogue
// fold-table float4s are loaded into registers BEFORE the corner loop, so
// their L1/L2 latency hides under the ~8-corner MAC chain instead of being
// exposed at the end of the point's dependency chain.
// (R12's F0-hoist + packed-butterfly bundle regressed -> reverted.)
// ---------------------------------------------------------------------------
__global__ __launch_bounds__(256)
void shdict_gather(const float* __restrict__ rays_o,
                   const float* __restrict__ rays_d,
                   const float* __restrict__ grid,
                   const float* __restrict__ atoms,
                   float* __restrict__ out,
                   float* __restrict__ ws)
{
  int bid = blockIdx.x;
  bid = (bid & 7) * (GATHER_BLOCKS / 8) + (bid >> 3);  // XCD swizzle

  const int ray  = bid / SEGS;
  const int seg  = bid - ray * SEGS;
  const int lane = threadIdx.x & 63;
  const int wv   = threadIdx.x >> 6;
  const int j    = seg * 4 + wv;          // sample index, < 224

  const float* rs = ws + WS_RAYDAT_OFF_F + ray*4;
  const float start = rs[0];
  const float jexit = rs[1];
  const float dist  = rs[2];

  if ((float)(seg*4) > jexit + 2.0f) return;   // conservative early-out

  const float ox = rays_o[ray*3+0], oy = rays_o[ray*3+1], oz = rays_o[ray*3+2];
  const float dx = rays_d[ray*3+0], dy = rays_d[ray*3+1], dz = rays_d[ray*3+2];

  const float t  = start + (float)j * STEP_F;
  const float px = ox + t*dx, py = oy + t*dy, pz = oz + t*dz;
  const bool inb = (px > -RAD) && (px < RAD) && (py > -RAD) && (py < RAD)
                && (pz > -RAD) && (pz < RAD);   // wave-uniform (1 pt/wave)

  float a = 0.f, r0 = 0.5f, r1 = 0.5f, r2 = 0.5f;

  if (inb) {
    // --- early tab preload: 8 independent loads, latency hidden by MACs ---
    const float4* tab = (const float4*)ws + WS_TAB_OFF_F4 + (size_t)ray * 512;
    const float4 T00 = tab[  0+lane], T01 = tab[ 64+lane];
    const float4 T10 = tab[128+lane], T11 = tab[192+lane];
    const float4 T20 = tab[256+lane], T21 = tab[320+lane];
    const float4 T30 = tab[384+lane], T31 = tab[448+lane];

    const float ux = (px + RAD) * INV_VOXEL;
    const float uy = (py + RAD) * INV_VOXEL;
    const float uz = (pz + RAD) * INV_VOXEL;

    const float pfx0 = fminf(fmaxf(floorf(ux - 0.5f), 0.0f), 127.0f);
    const float pfx1 = fminf(fmaxf(floorf(ux + 0.5f), 0.0f), 127.0f);
    const float pfy0 = fminf(fmaxf(floorf(uy - 0.5f), 0.0f), 127.0f);
    const float pfy1 = fminf(fmaxf(floorf(uy + 0.5f), 0.0f), 127.0f);
    const float pfz0 = fminf(fmaxf(floorf(uz - 0.5f), 0.0f), 127.0f);
    const float pfz1 = fminf(fmaxf(floorf(uz + 0.5f), 0.0f), 127.0f);
    const float wx0 = 1.0f - fabsf(ux - (pfx0 + 0.5f));
    const float wx1 = 1.0f - fabsf(ux - (pfx1 + 0.5f));
    const float wy0 = 1.0f - fabsf(uy - (pfy0 + 0.5f));
    const float wy1 = 1.0f - fabsf(uy - (pfy1 + 0.5f));
    const float wz0 = 1.0f - fabsf(uz - (pfz0 + 0.5f));
    const float wz1 = 1.0f - fabsf(uz - (pfz1 + 0.5f));
    const int ix0 = (int)pfx0, ix1 = (int)pfx1;
    const int iy0 = (int)pfy0, iy1 = (int)pfy1;
    const int iz0 = (int)pfz0, iz1 = (int)pfz1;
    const int cpx0 = (ix0 >> 2) * 114688, cpx1 = (ix1 >> 2) * 114688;
    const int cpy0 = (iy0 >> 2) * 3584,   cpy1 = (iy1 >> 2) * 3584;
    const int cpz0 = (iz0 >> 2) * 112,    cpz1 = (iz1 >> 2) * 112;
    const int fpx0 = (ix0 & 3) * 1792,    fpx1 = (ix1 & 3) * 1792;
    const int fpy0 = (iy0 & 3) * 448,     fpy1 = (iy1 & 3) * 448;
    const int fpz0 = (iz0 & 3) * 112,     fpz1 = (iz1 & 3) * 112;

    const float4* gp4 = (const float4*)grid;
    const float4* ap4 = (const float4*)atoms;

    float4 z4 = make_float4(0.f,0.f,0.f,0.f);
    float4 c0 = z4, c1 = z4;       // current coarse cell data
    float4 wf0 = z4, wf1 = z4;     // w-weighted fv accumulator (current group)
    float4 a0 = z4, a1 = z4;       // folded accumulators
    int pcell = -1;

    #define FOLD() {                                                          \
      a0.x = fmaf(c0.x, wf0.x, a0.x); a0.y = fmaf(c0.y, wf0.y, a0.y);         \
      a0.z = fmaf(c0.z, wf0.z, a0.z); a0.w = fmaf(c0.w, wf0.w, a0.w);         \
      a1.x = fmaf(c1.x, wf1.x, a1.x); a1.y = fmaf(c1.y, wf1.y, a1.y);         \
      a1.z = fmaf(c1.z, wf1.z, a1.z); a1.w = fmaf(c1.w, wf1.w, a1.w);         \
      wf0 = z4; wf1 = z4;                                                     \
    }
    #define CORNER(BX,BY,BZ)                                                  \
    {                                                                         \
      const int cp = (BX?cpx1:cpx0) + (BY?cpy1:cpy0) + (BZ?cpz1:cpz0);        \
      const float w = (BX?wx1:wx0) * (BY?wy1:wy0) * (BZ?wz1:wz0);             \
      if (cp != pcell) {                                                      \
        if (pcell >= 0) FOLD();                                               \
        const float4* cv = gp4 + cp;                                          \
        c0 = cv[lane];                                                        \
        if (lane < 48) c1 = cv[64 + lane];                                    \
        pcell = cp;                                                           \
      }                                                                       \
      const float4* fp = ap4 + ((BX?fpx1:fpx0) + (BY?fpy1:fpy0) + (BZ?fpz1:fpz0)); \
      const float4 f0 = fp[lane];                                             \
      wf0.x = fmaf(w, f0.x, wf0.x); wf0.y = fmaf(w, f0.y, wf0.y);             \
      wf0.z = fmaf(w, f0.z, wf0.z); wf0.w = fmaf(w, f0.w, wf0.w);             \
      if (lane < 48) {                                                        \
        const float4 f1 = fp[64 + lane];                                      \
        wf1.x = fmaf(w, f1.x, wf1.x); wf1.y = fmaf(w, f1.y, wf1.y);           \
        wf1.z = fmaf(w, f1.z, wf1.z); wf1.w = fmaf(w, f1.w, wf1.w);           \
      }                                                                       \
    }
    // gray order over (x,y,z): consecutive corners differ in one axis
    CORNER(0,0,0) CORNER(0,0,1) CORNER(0,1,1) CORNER(0,1,0)
    CORNER(1,1,0) CORNER(1,1,1) CORNER(1,0,1) CORNER(1,0,0)
    FOLD();
    #undef CORNER
    #undef FOLD

    // --- fold to (rgb_pre0..2, sigma) via preloaded tab regs, butterfly ---
    #define DOT4(K,V) ((K).x*(V).x + (K).y*(V).y + (K).z*(V).z + (K).w*(V).w)
    float b0 = DOT4(T00,a0) + DOT4(T01,a1);
    float b1 = DOT4(T10,a0) + DOT4(T11,a1);
    float b2 = DOT4(T20,a0) + DOT4(T21,a1);
    float b3 = DOT4(T30,a0) + DOT4(T31,a1);
    #undef DOT4
    #pragma unroll
    for (int off = 1; off < 64; off <<= 1) {
      b0 += __shfl_xor(b0, off, 64);
      b1 += __shfl_xor(b1, off, 64);
      b2 += __shfl_xor(b2, off, 64);
      b3 += __shfl_xor(b3, off, 64);
    }

    const float sigma = fmaxf(b3, 0.0f);
    a  = 1.0f - __expf(-sigma * dist);
    r0 = __builtin_amdgcn_rcpf(1.0f + __expf(-b0));
    r1 = __builtin_amdgcn_rcpf(1.0f + __expf(-b1));
    r2 = __builtin_amdgcn_rcpf(1.0f + __expf(-b2));
  }

  if (lane == 0) {
    out[NRAYS*3 + ray*NPT + j] = a;            // alpha output plane (j < 224)
    ws[0*WS_PLANE + ray*WS_RAY_STRIDE + j] = r0;
    ws[1*WS_PLANE + ray*WS_RAY_STRIDE + j] = r1;
    ws[2*WS_PLANE + ray*WS_RAY_STRIDE + j] = r2;
  }
}

// ---------------------------------------------------------------------------
// Scan: transmittance + reductions. One wave per ray; only j < 256 nonzero.
// ---------------------------------------------------------------------------
__global__ __launch_bounds__(256)
void shdict_scan(const float* __restrict__ rays_o,
                 const float* __restrict__ rays_d,
                 const float* __restrict__ ws,
                 float* __restrict__ out)
{
  const int wave = threadIdx.x >> 6;
  const int lane = threadIdx.x & 63;
  const int ray  = blockIdx.x * 4 + wave;
  if (ray >= NRAYS) return;

  const float ox = rays_o[ray*3+0], oy = rays_o[ray*3+1], oz = rays_o[ray*3+2];
  const float dx = rays_d[ray*3+0], dy = rays_d[ray*3+1], dz = rays_d[ray*3+2];
  const float m0 = fminf((RAD - ox)/dx, (-RAD - ox)/dx);
  const float m1 = fminf((RAD - oy)/dy, (-RAD - oy)/dy);
  const float m2 = fminf((RAD - oz)/dz, (-RAD - oz)/dz);
  const float start = fmaxf(fmaxf(m0, m1), m2);

  const float* alpha = out + NRAYS*3 + ray*NPT;

  float carry = 1.0f;
  float acc = 0.f, dep = 0.f, c0 = 0.f, c1 = 0.f, c2 = 0.f;
  for (int chunk = 0; chunk < 4; ++chunk) {
    const int j = chunk*64 + lane;
    const float a = alpha[j];
    const float v = 1.0f - a + 1e-10f;
    float s = v;
    #pragma unroll
    for (int off = 1; off < 64; off <<= 1) {
      const float o = __shfl_up(s, off, 64);
      if (lane >= off) s *= o;
    }
    float excl = __shfl_up(s, 1, 64);
    if (lane == 0) excl = 1.0f;
    const float T = carry * excl;
    const float al = a * T;
    acc += al;
    const float t = start + (float)j * STEP_F;
    dep += al * t;
    c0 += al * ws[0*WS_PLANE + ray*WS_RAY_STRIDE + j];
    c1 += al * ws[1*WS_PLANE + ray*WS_RAY_STRIDE + j];
    c2 += al * ws[2*WS_PLANE + ray*WS_RAY_STRIDE + j];
    carry *= __shfl(s, 63, 64);
  }
  #pragma unroll
  for (int off = 32; off >= 1; off >>= 1) {
    acc += __shfl_down(acc, off, 64);
    dep += __shfl_down(dep, off, 64);
    c0  += __shfl_down(c0,  off, 64);
    c1  += __shfl_down(c1,  off, 64);
    c2  += __shfl_down(c2,  off, 64);
  }
  if (lane == 0) {
    const float bg = 1.0f - acc;
    out[ray*3+0] = c0 + bg;
    out[ray*3+1] = c1 + bg;
    out[ray*3+2] = c2 + bg;
    out[NRAYS*3 + NRAYS*NPT + ray] = dep;
    if (ray == 0) out[NRAYS*3 + NRAYS*NPT + NRAYS] = 0.0f;
  }
}

// ---------------------------------------------------------------------------
// Fallback: fused single-kernel version (used only if ws is too small).
// ---------------------------------------------------------------------------
__global__ __launch_bounds__(256)
void shdict_render_fused(const float* __restrict__ rays_o,
                         const float* __restrict__ rays_d,
                         const float* __restrict__ grid,
                         const float* __restrict__ atoms,
                         float* __restrict__ out)
{
  const int ray = blockIdx.x;
  const int tid = threadIdx.x;

  __shared__ float s_alpha[NPT];
  __shared__ float s_rgb[NPT][3];

  const float ox = rays_o[ray*3+0], oy = rays_o[ray*3+1], oz = rays_o[ray*3+2];
  const float dx = rays_d[ray*3+0], dy = rays_d[ray*3+1], dz = rays_d[ray*3+2];

  const float m0 = fminf((RAD - ox)/dx, (-RAD - ox)/dx);
  const float m1 = fminf((RAD - oy)/dy, (-RAD - oy)/dy);
  const float m2 = fminf((RAD - oz)/dz, (-RAD - oz)/dz);
  const float start = fmaxf(fmaxf(m0, m1), m2);

  const float dnorm = sqrtf(dx*dx + dy*dy + dz*dz);
  const float inx = dx/dnorm, iny = dy/dnorm, inz = dz/dnorm;
  float sh[9];
  sh[0] = 0.28209479177387814f;
  sh[1] = -0.4886025119029199f*iny;
  sh[2] =  0.4886025119029199f*inz;
  sh[3] = -0.4886025119029199f*inx;
  sh[4] =  1.0925484305920792f*inx*iny;
  sh[5] = -1.0925484305920792f*iny*inz;
  sh[6] =  0.31539156525252005f*(2.0f*inz*inz - inx*inx - iny*iny);
  sh[7] = -1.0925484305920792f*inx*inz;
  sh[8] =  0.5462742152960396f*(inx*inx - iny*iny);

  float* alpha_out = out + NRAYS*3;

  for (int j = tid; j < NPT; j += 256) {
    const float t  = start + (float)j * STEP_F;
    const float px = ox + t*dx;
    const float py = oy + t*dy;
    const float pz = oz + t*dz;
    const bool inb = (px > -RAD) && (px < RAD) && (py > -RAD) && (py < RAD)
                  && (pz > -RAD) && (pz < RAD);
    float a = 0.0f, r0 = 0.5f, r1 = 0.5f, r2 = 0.5f;
    if (inb) {
      const float ux = (px + RAD) / VOXEL_F;
      const float uy = (py + RAD) / VOXEL_F;
      const float uz = (pz + RAD) / VOXEL_F;
      float4 acc4[7];
      #pragma unroll
      for (int q = 0; q < 7; ++q) acc4[q] = make_float4(0.f,0.f,0.f,0.f);
      for (int corner = 0; corner < 8; ++corner) {
        const float sx = (corner & 4) ? 0.5f : -0.5f;
        const float sy = (corner & 2) ? 0.5f : -0.5f;
        const float sz = (corner & 1) ? 0.5f : -0.5f;
        const float pfx = fminf(fmaxf(floorf(ux + sx), 0.0f), 127.0f);
        const float pfy = fminf(fmaxf(floorf(uy + sy), 0.0f), 127.0f);
        const float pfz = fminf(fmaxf(floorf(uz + sz), 0.0f), 127.0f);
        const float fx = fabsf(ux - (pfx + 0.5f));
        const float fy = fabsf(uy - (pfy + 0.5f));
        const float fz = fabsf(uz - (pfz + 0.5f));
        const float w = (1.0f-fx)*(1.0f-fy)*(1.0f-fz);
        const int ix = (int)pfx, iy = (int)pfy, iz = (int)pfz;
        const int cell = ((ix >> 2)*COARSE + (iy >> 2))*COARSE + (iz >> 2);
        const int fine = ((ix & 3)*4 + (iy & 3))*4 + (iz & 3);
        const float4* cv = (const float4*)(grid + (long)cell*448);
        const float4* fv = (const float4*)(atoms + (long)fine*448);
        float4 res[7];
        #pragma unroll
        for (int q = 0; q < 7; ++q) res[q] = make_float4(0.f,0.f,0.f,0.f);
        for (int aa = 0; aa < 16; ++aa) {
          #pragma unroll
          for (int q = 0; q < 7; ++q) {
            const float4 c = cv[aa*7 + q];
            const float4 f = fv[aa*7 + q];
            res[q].x += c.x*f.x;
            res[q].y += c.y*f.y;
            res[q].z += c.z*f.z;
            res[q].w += c.w*f.w;
          }
        }
        #pragma unroll
        for (int q = 0; q < 7; ++q) {
          acc4[q].x += w*res[q].x;
          acc4[q].y += w*res[q].y;
          acc4[q].z += w*res[q].z;
          acc4[q].w += w*res[q].w;
        }
      }
      const float* data = (const float*)acc4;
      const float sigma = fmaxf(data[27], 0.0f);
      a = 1.0f - expf(-sigma * (STEP_F * dnorm));
      float p0 = 0.f, p1 = 0.f, p2 = 0.f;
      #pragma unroll
      for (int k = 0; k < 9; ++k) {
        p0 += sh[k]*data[k];
        p1 += sh[k]*data[9+k];
        p2 += sh[k]*data[18+k];
      }
      r0 = 1.0f/(1.0f + expf(-p0));
      r1 = 1.0f/(1.0f + expf(-p1));
      r2 = 1.0f/(1.0f + expf(-p2));
    }
    s_alpha[j]  = a;
    s_rgb[j][0] = r0; s_rgb[j][1] = r1; s_rgb[j][2] = r2;
    alpha_out[ray*NPT + j] = a;
  }
  __syncthreads();

  if (tid < 64) {
    const int lane = tid;
    float carry = 1.0f;
    float acc = 0.f, dep = 0.f, c0 = 0.f, c1 = 0.f, c2 = 0.f;
    for (int chunk = 0; chunk < 12; ++chunk) {
      const int j = chunk*64 + lane;
      const float a = (j < NPT) ? s_alpha[j] : 0.0f;
      const float v = 1.0f - a + 1e-10f;
      float s = v;
      #pragma unroll
      for (int off = 1; off < 64; off <<= 1) {
        const float o = __shfl_up(s, off, 64);
        if (lane >= off) s *= o;
      }
      float excl = __shfl_up(s, 1, 64);
      if (lane == 0) excl = 1.0f;
      const float T = carry * excl;
      if (j < NPT) {
        const float al = a * T;
        acc += al;
        dep += al * (start + (float)j * STEP_F);
        c0 += al * s_rgb[j][0];
        c1 += al * s_rgb[j][1];
        c2 += al * s_rgb[j][2];
      }
      carry *= __shfl(s, 63, 64);
    }
    #pragma unroll
    for (int off = 32; off >= 1; off >>= 1) {
      acc += __shfl_down(acc, off, 64);
      dep += __shfl_down(dep, off, 64);
      c0  += __shfl_down(c0,  off, 64);
      c1  += __shfl_down(c1,  off, 64);
      c2  += __shfl_down(c2,  off, 64);
    }
    if (lane == 0) {
      const float bg = 1.0f - acc;
      out[ray*3+0] = c0 + bg;
      out[ray*3+1] = c1 + bg;
      out[ray*3+2] = c2 + bg;
      out[NRAYS*3 + NRAYS*NPT + ray] = dep;
      if (ray == 0) out[NRAYS*3 + NRAYS*NPT + NRAYS] = 0.0f;
    }
  }
}

extern "C" void kernel_launch(void* const* d_in, const int* in_sizes, int n_in,
                              void* d_out, int out_size, void* d_ws, size_t ws_size,
                              hipStream_t stream) {
  const float* rays_o = (const float*)d_in[0];
  const float* rays_d = (const float*)d_in[1];
  const float* grid   = (const float*)d_in[2];
  const float* atoms  = (const float*)d_in[3];
  (void)in_sizes; (void)n_in;

  // alpha plane for j >= 224 must be exactly 0 (the reference value there)
  hipMemsetAsync(d_out, 0, (size_t)out_size * sizeof(float), stream);

  const size_t ws_needed = (size_t)(WS_RAYDAT_OFF_F + NRAYS*4) * sizeof(float);
  if (ws_size >= ws_needed) {
    hipLaunchKernelGGL(shdict_init, dim3(NRAYS), dim3(256), 0, stream,
                       rays_o, rays_d, (float*)d_ws);
    hipLaunchKernelGGL(shdict_gather, dim3(GATHER_BLOCKS), dim3(256), 0, stream,
                       rays_o, rays_d, grid, atoms, (float*)d_out, (float*)d_ws);
    hipLaunchKernelGGL(shdict_scan, dim3(NRAYS/4), dim3(256), 0, stream,
                       rays_o, rays_d, (const float*)d_ws, (float*)d_out);
  } else {
    hipLaunchKernelGGL(shdict_render_fused, dim3(NRAYS), dim3(256), 0, stream,
                       rays_o, rays_d, grid, atoms, (float*)d_out);
  }
}

// Round 14
// 73.094 us; speedup vs baseline: 1.0856x; 1.0856x over previous
//
#include <hip/hip_runtime.h>
#include <math.h>

namespace {
constexpr int COARSE = 32;
constexpr int NPT    = 767;   // N_INT - 1
constexpr int NRAYS  = 256;
constexpr int JMAX   = 224;                    // j < 221.7 provable in-cube bound
constexpr int SEGS   = JMAX / 4;               // 56 (4 waves/block, 1 pt/wave)
constexpr int GATHER_BLOCKS = NRAYS * SEGS;    // 14336 (% 8 == 0)
constexpr int WS_RAY_STRIDE = 256;
constexpr int WS_PLANE = NRAYS * WS_RAY_STRIDE;            // 65536 floats/plane
constexpr int WS_TAB_OFF_F4 = (3 * WS_PLANE) / 4;          // 49152 (float4 idx)
constexpr int WS_RAYDAT_OFF_F = 3 * WS_PLANE + NRAYS*512*4; // 720896 (float idx)
constexpr double VOXEL_D = 1.3 * 2.0 / 32.0 / 4.0;
constexpr float  VOXEL_F  = (float)VOXEL_D;
constexpr float  INV_VOXEL = (float)(1.0 / VOXEL_D);
constexpr float  STEP_F   = (float)(VOXEL_D / 2.0);
constexpr float  RAD      = 1.3f;
}

// ---------------------------------------------------------------------------
// Init: one block per ray. {start, jexit, dist} + per-ray 512-float4 fold
// table into ws (removes table build + divides from the 14336-block gather).
// ---------------------------------------------------------------------------
__global__ __launch_bounds__(256)
void shdict_init(const float* __restrict__ rays_o,
                 const float* __restrict__ rays_d,
                 float* __restrict__ ws)
{
  const int ray = blockIdx.x;
  const float ox = rays_o[ray*3+0], oy = rays_o[ray*3+1], oz = rays_o[ray*3+2];
  const float dx = rays_d[ray*3+0], dy = rays_d[ray*3+1], dz = rays_d[ray*3+2];

  const float ax0 = (RAD - ox)/dx, ax1 = (-RAD - ox)/dx;
  const float ay0 = (RAD - oy)/dy, ay1 = (-RAD - oy)/dy;
  const float az0 = (RAD - oz)/dz, az1 = (-RAD - oz)/dz;
  const float start = fmaxf(fmaxf(fminf(ax0,ax1), fminf(ay0,ay1)), fminf(az0,az1));
  const float texit = fminf(fminf(fmaxf(ax0,ax1), fmaxf(ay0,ay1)), fmaxf(az0,az1));
  const float dnorm = sqrtf(dx*dx + dy*dy + dz*dz);
  const float inx = dx/dnorm, iny = dy/dnorm, inz = dz/dnorm;

  if (threadIdx.x == 0) {
    float* rs = ws + WS_RAYDAT_OFF_F + ray*4;
    rs[0] = start;
    rs[1] = (texit - start) / STEP_F;   // jexit
    rs[2] = STEP_F * dnorm;             // dist
    rs[3] = 0.f;
  }

  float4* tab = (float4*)ws + WS_TAB_OFF_F4 + (size_t)ray * 512;
  for (int tix = threadIdx.x; tix < 512; tix += 256) {
    const int ch = tix >> 7;
    const int fi = tix & 127;
    float vv[4];
    #pragma unroll
    for (int comp = 0; comp < 4; ++comp) {
      float val = 0.f;
      if (fi < 112) {
        const int e = 4*fi + comp;
        const int d = e % 28;
        const int dm = d % 9;
        const float shv =
          dm==0 ?  0.28209479177387814f :
          dm==1 ? -0.4886025119029199f*iny :
          dm==2 ?  0.4886025119029199f*inz :
          dm==3 ? -0.4886025119029199f*inx :
          dm==4 ?  1.0925484305920792f*inx*iny :
          dm==5 ? -1.0925484305920792f*iny*inz :
          dm==6 ?  0.31539156525252005f*(2.0f*inz*inz - inx*inx - iny*iny) :
          dm==7 ? -1.0925484305920792f*inx*inz :
                   0.5462742152960396f*(inx*inx - iny*iny);
        if (d == 27) { if (ch == 3) val = 1.0f; }
        else if (d/9 == ch) val = shv;
      }
      vv[comp] = val;
    }
    float4 v; v.x = vv[0]; v.y = vv[1]; v.z = vv[2]; v.w = vv[3];
    tab[tix] = v;
  }
}

// ---------------------------------------------------------------------------
// Gather: R11 champion structure, restored verbatim. One 64-lane wave per
// point, j < 224. No divides, no LDS, no table build. wfv-factored corner
// loop (wf += w*fv per corner; fold a += cv.wf once per coarse-cell group).
// Epilogue fold-table read from L2 at natural (compiler-chosen) position —
// R12 (fv bulk-hoist) and R13 (tab preload) both regressed: added live
// state drops achieved occupancy faster than it hides latency.
// ---------------------------------------------------------------------------
__global__ __launch_bounds__(256)
void shdict_gather(const float* __restrict__ rays_o,
                   const float* __restrict__ rays_d,
                   const float* __restrict__ grid,
                   const float* __restrict__ atoms,
                   float* __restrict__ out,
                   float* __restrict__ ws)
{
  int bid = blockIdx.x;
  bid = (bid & 7) * (GATHER_BLOCKS / 8) + (bid >> 3);  // XCD swizzle

  const int ray  = bid / SEGS;
  const int seg  = bid - ray * SEGS;
  const int lane = threadIdx.x & 63;
  const int wv   = threadIdx.x >> 6;
  const int j    = seg * 4 + wv;          // sample index, < 224

  const float* rs = ws + WS_RAYDAT_OFF_F + ray*4;
  const float start = rs[0];
  const float jexit = rs[1];
  const float dist  = rs[2];

  if ((float)(seg*4) > jexit + 2.0f) return;   // conservative early-out

  const float ox = rays_o[ray*3+0], oy = rays_o[ray*3+1], oz = rays_o[ray*3+2];
  const float dx = rays_d[ray*3+0], dy = rays_d[ray*3+1], dz = rays_d[ray*3+2];

  const float t  = start + (float)j * STEP_F;
  const float px = ox + t*dx, py = oy + t*dy, pz = oz + t*dz;
  const bool inb = (px > -RAD) && (px < RAD) && (py > -RAD) && (py < RAD)
                && (pz > -RAD) && (pz < RAD);   // wave-uniform (1 pt/wave)

  float a = 0.f, r0 = 0.5f, r1 = 0.5f, r2 = 0.5f;

  if (inb) {
    const float ux = (px + RAD) * INV_VOXEL;
    const float uy = (py + RAD) * INV_VOXEL;
    const float uz = (pz + RAD) * INV_VOXEL;

    const float pfx0 = fminf(fmaxf(floorf(ux - 0.5f), 0.0f), 127.0f);
    const float pfx1 = fminf(fmaxf(floorf(ux + 0.5f), 0.0f), 127.0f);
    const float pfy0 = fminf(fmaxf(floorf(uy - 0.5f), 0.0f), 127.0f);
    const float pfy1 = fminf(fmaxf(floorf(uy + 0.5f), 0.0f), 127.0f);
    const float pfz0 = fminf(fmaxf(floorf(uz - 0.5f), 0.0f), 127.0f);
    const float pfz1 = fminf(fmaxf(floorf(uz + 0.5f), 0.0f), 127.0f);
    const float wx0 = 1.0f - fabsf(ux - (pfx0 + 0.5f));
    const float wx1 = 1.0f - fabsf(ux - (pfx1 + 0.5f));
    const float wy0 = 1.0f - fabsf(uy - (pfy0 + 0.5f));
    const float wy1 = 1.0f - fabsf(uy - (pfy1 + 0.5f));
    const float wz0 = 1.0f - fabsf(uz - (pfz0 + 0.5f));
    const float wz1 = 1.0f - fabsf(uz - (pfz1 + 0.5f));
    const int ix0 = (int)pfx0, ix1 = (int)pfx1;
    const int iy0 = (int)pfy0, iy1 = (int)pfy1;
    const int iz0 = (int)pfz0, iz1 = (int)pfz1;
    const int cpx0 = (ix0 >> 2) * 114688, cpx1 = (ix1 >> 2) * 114688;
    const int cpy0 = (iy0 >> 2) * 3584,   cpy1 = (iy1 >> 2) * 3584;
    const int cpz0 = (iz0 >> 2) * 112,    cpz1 = (iz1 >> 2) * 112;
    const int fpx0 = (ix0 & 3) * 1792,    fpx1 = (ix1 & 3) * 1792;
    const int fpy0 = (iy0 & 3) * 448,     fpy1 = (iy1 & 3) * 448;
    const int fpz0 = (iz0 & 3) * 112,    fpz1 = (iz1 & 3) * 112;

    const float4* gp4 = (const float4*)grid;
    const float4* ap4 = (const float4*)atoms;

    float4 z4 = make_float4(0.f,0.f,0.f,0.f);
    float4 c0 = z4, c1 = z4;       // current coarse cell data
    float4 wf0 = z4, wf1 = z4;     // w-weighted fv accumulator (current group)
    float4 a0 = z4, a1 = z4;       // folded accumulators
    int pcell = -1;

    #define FOLD() {                                                          \
      a0.x = fmaf(c0.x, wf0.x, a0.x); a0.y = fmaf(c0.y, wf0.y, a0.y);         \
      a0.z = fmaf(c0.z, wf0.z, a0.z); a0.w = fmaf(c0.w, wf0.w, a0.w);         \
      a1.x = fmaf(c1.x, wf1.x, a1.x); a1.y = fmaf(c1.y, wf1.y, a1.y);         \
      a1.z = fmaf(c1.z, wf1.z, a1.z); a1.w = fmaf(c1.w, wf1.w, a1.w);         \
      wf0 = z4; wf1 = z4;                                                     \
    }
    #define CORNER(BX,BY,BZ)                                                  \
    {                                                                         \
      const int cp = (BX?cpx1:cpx0) + (BY?cpy1:cpy0) + (BZ?cpz1:cpz0);        \
      const float w = (BX?wx1:wx0) * (BY?wy1:wy0) * (BZ?wz1:wz0);             \
      if (cp != pcell) {                                                      \
        if (pcell >= 0) FOLD();                                               \
        const float4* cv = gp4 + cp;                                          \
        c0 = cv[lane];                                                        \
        if (lane < 48) c1 = cv[64 + lane];                                    \
        pcell = cp;                                                           \
      }                                                                       \
      const float4* fp = ap4 + ((BX?fpx1:fpx0) + (BY?fpy1:fpy0) + (BZ?fpz1:fpz0)); \
      const float4 f0 = fp[lane];                                             \
      wf0.x = fmaf(w, f0.x, wf0.x); wf0.y = fmaf(w, f0.y, wf0.y);             \
      wf0.z = fmaf(w, f0.z, wf0.z); wf0.w = fmaf(w, f0.w, wf0.w);             \
      if (lane < 48) {                                                        \
        const float4 f1 = fp[64 + lane];                                      \
        wf1.x = fmaf(w, f1.x, wf1.x); wf1.y = fmaf(w, f1.y, wf1.y);           \
        wf1.z = fmaf(w, f1.z, wf1.z); wf1.w = fmaf(w, f1.w, wf1.w);           \
      }                                                                       \
    }
    // gray order over (x,y,z): consecutive corners differ in one axis
    CORNER(0,0,0) CORNER(0,0,1) CORNER(0,1,1) CORNER(0,1,0)
    CORNER(1,1,0) CORNER(1,1,1) CORNER(1,0,1) CORNER(1,0,0)
    FOLD();
    #undef CORNER
    #undef FOLD

    // --- fold to (rgb_pre0..2, sigma) via per-ray table (L2), butterfly ---
    const float4* tab = (const float4*)ws + WS_TAB_OFF_F4 + (size_t)ray * 512;
    #define DOT4(K,V) ((K).x*(V).x + (K).y*(V).y + (K).z*(V).z + (K).w*(V).w)
    float b0 = DOT4(tab[  0+lane],a0) + DOT4(tab[ 64+lane],a1);
    float b1 = DOT4(tab[128+lane],a0) + DOT4(tab[192+lane],a1);
    float b2 = DOT4(tab[256+lane],a0) + DOT4(tab[320+lane],a1);
    float b3 = DOT4(tab[384+lane],a0) + DOT4(tab[448+lane],a1);
    #undef DOT4
    #pragma unroll
    for (int off = 1; off < 64; off <<= 1) {
      b0 += __shfl_xor(b0, off, 64);
      b1 += __shfl_xor(b1, off, 64);
      b2 += __shfl_xor(b2, off, 64);
      b3 += __shfl_xor(b3, off, 64);
    }

    const float sigma = fmaxf(b3, 0.0f);
    a  = 1.0f - __expf(-sigma * dist);
    r0 = __builtin_amdgcn_rcpf(1.0f + __expf(-b0));
    r1 = __builtin_amdgcn_rcpf(1.0f + __expf(-b1));
    r2 = __builtin_amdgcn_rcpf(1.0f + __expf(-b2));
  }

  if (lane == 0) {
    out[NRAYS*3 + ray*NPT + j] = a;            // alpha output plane (j < 224)
    ws[0*WS_PLANE + ray*WS_RAY_STRIDE + j] = r0;
    ws[1*WS_PLANE + ray*WS_RAY_STRIDE + j] = r1;
    ws[2*WS_PLANE + ray*WS_RAY_STRIDE + j] = r2;
  }
}

// ---------------------------------------------------------------------------
// Scan: transmittance + reductions. One wave per ray; only j < 256 nonzero.
// ---------------------------------------------------------------------------
__global__ __launch_bounds__(256)
void shdict_scan(const float* __restrict__ rays_o,
                 const float* __restrict__ rays_d,
                 const float* __restrict__ ws,
                 float* __restrict__ out)
{
  const int wave = threadIdx.x >> 6;
  const int lane = threadIdx.x & 63;
  const int ray  = blockIdx.x * 4 + wave;
  if (ray >= NRAYS) return;

  const float ox = rays_o[ray*3+0], oy = rays_o[ray*3+1], oz = rays_o[ray*3+2];
  const float dx = rays_d[ray*3+0], dy = rays_d[ray*3+1], dz = rays_d[ray*3+2];
  const float m0 = fminf((RAD - ox)/dx, (-RAD - ox)/dx);
  const float m1 = fminf((RAD - oy)/dy, (-RAD - oy)/dy);
  const float m2 = fminf((RAD - oz)/dz, (-RAD - oz)/dz);
  const float start = fmaxf(fmaxf(m0, m1), m2);

  const float* alpha = out + NRAYS*3 + ray*NPT;

  float carry = 1.0f;
  float acc = 0.f, dep = 0.f, c0 = 0.f, c1 = 0.f, c2 = 0.f;
  for (int chunk = 0; chunk < 4; ++chunk) {
    const int j = chunk*64 + lane;
    const float a = alpha[j];
    const float v = 1.0f - a + 1e-10f;
    float s = v;
    #pragma unroll
    for (int off = 1; off < 64; off <<= 1) {
      const float o = __shfl_up(s, off, 64);
      if (lane >= off) s *= o;
    }
    float excl = __shfl_up(s, 1, 64);
    if (lane == 0) excl = 1.0f;
    const float T = carry * excl;
    const float al = a * T;
    acc += al;
    const float t = start + (float)j * STEP_F;
    dep += al * t;
    c0 += al * ws[0*WS_PLANE + ray*WS_RAY_STRIDE + j];
    c1 += al * ws[1*WS_PLANE + ray*WS_RAY_STRIDE + j];
    c2 += al * ws[2*WS_PLANE + ray*WS_RAY_STRIDE + j];
    carry *= __shfl(s, 63, 64);
  }
  #pragma unroll
  for (int off = 32; off >= 1; off >>= 1) {
    acc += __shfl_down(acc, off, 64);
    dep += __shfl_down(dep, off, 64);
    c0  += __shfl_down(c0,  off, 64);
    c1  += __shfl_down(c1,  off, 64);
    c2  += __shfl_down(c2,  off, 64);
  }
  if (lane == 0) {
    const float bg = 1.0f - acc;
    out[ray*3+0] = c0 + bg;
    out[ray*3+1] = c1 + bg;
    out[ray*3+2] = c2 + bg;
    out[NRAYS*3 + NRAYS*NPT + ray] = dep;
    if (ray == 0) out[NRAYS*3 + NRAYS*NPT + NRAYS] = 0.0f;
  }
}

// ---------------------------------------------------------------------------
// Fallback: fused single-kernel version (used only if ws is too small).
// ---------------------------------------------------------------------------
__global__ __launch_bounds__(256)
void shdict_render_fused(const float* __restrict__ rays_o,
                         const float* __restrict__ rays_d,
                         const float* __restrict__ grid,
                         const float* __restrict__ atoms,
                         float* __restrict__ out)
{
  const int ray = blockIdx.x;
  const int tid = threadIdx.x;

  __shared__ float s_alpha[NPT];
  __shared__ float s_rgb[NPT][3];

  const float ox = rays_o[ray*3+0], oy = rays_o[ray*3+1], oz = rays_o[ray*3+2];
  const float dx = rays_d[ray*3+0], dy = rays_d[ray*3+1], dz = rays_d[ray*3+2];

  const float m0 = fminf((RAD - ox)/dx, (-RAD - ox)/dx);
  const float m1 = fminf((RAD - oy)/dy, (-RAD - oy)/dy);
  const float m2 = fminf((RAD - oz)/dz, (-RAD - oz)/dz);
  const float start = fmaxf(fmaxf(m0, m1), m2);

  const float dnorm = sqrtf(dx*dx + dy*dy + dz*dz);
  const float inx = dx/dnorm, iny = dy/dnorm, inz = dz/dnorm;
  float sh[9];
  sh[0] = 0.28209479177387814f;
  sh[1] = -0.4886025119029199f*iny;
  sh[2] =  0.4886025119029199f*inz;
  sh[3] = -0.4886025119029199f*inx;
  sh[4] =  1.0925484305920792f*inx*iny;
  sh[5] = -1.0925484305920792f*iny*inz;
  sh[6] =  0.31539156525252005f*(2.0f*inz*inz - inx*inx - iny*iny);
  sh[7] = -1.0925484305920792f*inx*inz;
  sh[8] =  0.5462742152960396f*(inx*inx - iny*iny);

  float* alpha_out = out + NRAYS*3;

  for (int j = tid; j < NPT; j += 256) {
    const float t  = start + (float)j * STEP_F;
    const float px = ox + t*dx;
    const float py = oy + t*dy;
    const float pz = oz + t*dz;
    const bool inb = (px > -RAD) && (px < RAD) && (py > -RAD) && (py < RAD)
                  && (pz > -RAD) && (pz < RAD);
    float a = 0.0f, r0 = 0.5f, r1 = 0.5f, r2 = 0.5f;
    if (inb) {
      const float ux = (px + RAD) / VOXEL_F;
      const float uy = (py + RAD) / VOXEL_F;
      const float uz = (pz + RAD) / VOXEL_F;
      float4 acc4[7];
      #pragma unroll
      for (int q = 0; q < 7; ++q) acc4[q] = make_float4(0.f,0.f,0.f,0.f);
      for (int corner = 0; corner < 8; ++corner) {
        const float sx = (corner & 4) ? 0.5f : -0.5f;
        const float sy = (corner & 2) ? 0.5f : -0.5f;
        const float sz = (corner & 1) ? 0.5f : -0.5f;
        const float pfx = fminf(fmaxf(floorf(ux + sx), 0.0f), 127.0f);
        const float pfy = fminf(fmaxf(floorf(uy + sy), 0.0f), 127.0f);
        const float pfz = fminf(fmaxf(floorf(uz + sz), 0.0f), 127.0f);
        const float fx = fabsf(ux - (pfx + 0.5f));
        const float fy = fabsf(uy - (pfy + 0.5f));
        const float fz = fabsf(uz - (pfz + 0.5f));
        const float w = (1.0f-fx)*(1.0f-fy)*(1.0f-fz);
        const int ix = (int)pfx, iy = (int)pfy, iz = (int)pfz;
        const int cell = ((ix >> 2)*COARSE + (iy >> 2))*COARSE + (iz >> 2);
        const int fine = ((ix & 3)*4 + (iy & 3))*4 + (iz & 3);
        const float4* cv = (const float4*)(grid + (long)cell*448);
        const float4* fv = (const float4*)(atoms + (long)fine*448);
        float4 res[7];
        #pragma unroll
        for (int q = 0; q < 7; ++q) res[q] = make_float4(0.f,0.f,0.f,0.f);
        for (int aa = 0; aa < 16; ++aa) {
          #pragma unroll
          for (int q = 0; q < 7; ++q) {
            const float4 c = cv[aa*7 + q];
            const float4 f = fv[aa*7 + q];
            res[q].x += c.x*f.x;
            res[q].y += c.y*f.y;
            res[q].z += c.z*f.z;
            res[q].w += c.w*f.w;
          }
        }
        #pragma unroll
        for (int q = 0; q < 7; ++q) {
          acc4[q].x += w*res[q].x;
          acc4[q].y += w*res[q].y;
          acc4[q].z += w*res[q].z;
          acc4[q].w += w*res[q].w;
        }
      }
      const float* data = (const float*)acc4;
      const float sigma = fmaxf(data[27], 0.0f);
      a = 1.0f - expf(-sigma * (STEP_F * dnorm));
      float p0 = 0.f, p1 = 0.f, p2 = 0.f;
      #pragma unroll
      for (int k = 0; k < 9; ++k) {
        p0 += sh[k]*data[k];
        p1 += sh[k]*data[9+k];
        p2 += sh[k]*data[18+k];
      }
      r0 = 1.0f/(1.0f + expf(-p0));
      r1 = 1.0f/(1.0f + expf(-p1));
      r2 = 1.0f/(1.0f + expf(-p2));
    }
    s_alpha[j]  = a;
    s_rgb[j][0] = r0; s_rgb[j][1] = r1; s_rgb[j][2] = r2;
    alpha_out[ray*NPT + j] = a;
  }
  __syncthreads();

  if (tid < 64) {
    const int lane = tid;
    float carry = 1.0f;
    float acc = 0.f, dep = 0.f, c0 = 0.f, c1 = 0.f, c2 = 0.f;
    for (int chunk = 0; chunk < 12; ++chunk) {
      const int j = chunk*64 + lane;
      const float a = (j < NPT) ? s_alpha[j] : 0.0f;
      const float v = 1.0f - a + 1e-10f;
      float s = v;
      #pragma unroll
      for (int off = 1; off < 64; off <<= 1) {
        const float o = __shfl_up(s, off, 64);
        if (lane >= off) s *= o;
      }
      float excl = __shfl_up(s, 1, 64);
      if (lane == 0) excl = 1.0f;
      const float T = carry * excl;
      if (j < NPT) {
        const float al = a * T;
        acc += al;
        dep += al * (start + (float)j * STEP_F);
        c0 += al * s_rgb[j][0];
        c1 += al * s_rgb[j][1];
        c2 += al * s_rgb[j][2];
      }
      carry *= __shfl(s, 63, 64);
    }
    #pragma unroll
    for (int off = 32; off >= 1; off >>= 1) {
      acc += __shfl_down(acc, off, 64);
      dep += __shfl_down(dep, off, 64);
      c0  += __shfl_down(c0,  off, 64);
      c1  += __shfl_down(c1,  off, 64);
      c2  += __shfl_down(c2,  off, 64);
    }
    if (lane == 0) {
      const float bg = 1.0f - acc;
      out[ray*3+0] = c0 + bg;
      out[ray*3+1] = c1 + bg;
      out[ray*3+2] = c2 + bg;
      out[NRAYS*3 + NRAYS*NPT + ray] = dep;
      if (ray == 0) out[NRAYS*3 + NRAYS*NPT + NRAYS] = 0.0f;
    }
  }
}

extern "C" void kernel_launch(void* const* d_in, const int* in_sizes, int n_in,
                              void* d_out, int out_size, void* d_ws, size_t ws_size,
                              hipStream_t stream) {
  const float* rays_o = (const float*)d_in[0];
  const float* rays_d = (const float*)d_in[1];
  const float* grid   = (const float*)d_in[2];
  const float* atoms  = (const float*)d_in[3];
  (void)in_sizes; (void)n_in;

  // alpha plane for j >= 224 must be exactly 0 (the reference value there)
  hipMemsetAsync(d_out, 0, (size_t)out_size * sizeof(float), stream);

  const size_t ws_needed = (size_t)(WS_RAYDAT_OFF_F + NRAYS*4) * sizeof(float);
  if (ws_size >= ws_needed) {
    hipLaunchKernelGGL(shdict_init, dim3(NRAYS), dim3(256), 0, stream,
                       rays_o, rays_d, (float*)d_ws);
    hipLaunchKernelGGL(shdict_gather, dim3(GATHER_BLOCKS), dim3(256), 0, stream,
                       rays_o, rays_d, grid, atoms, (float*)d_out, (float*)d_ws);
    hipLaunchKernelGGL(shdict_scan, dim3(NRAYS/4), dim3(256), 0, stream,
                       rays_o, rays_d, (const float*)d_ws, (float*)d_out);
  } else {
    hipLaunchKernelGGL(shdict_render_fused, dim3(NRAYS), dim3(256), 0, stream,
                       rays_o, rays_d, grid, atoms, (float*)d_out);
  }
}